// Round 2
// baseline (610.205 us; speedup 1.0000x reference)
//
#include <hip/hip_runtime.h>
#include <math.h>

typedef __attribute__((ext_vector_type(8))) short bf8_t;   // 8 bf16 in 4 VGPRs
typedef __attribute__((ext_vector_type(4))) float f4_t;    // MFMA C/D frag

#define MFMA(a,b,c) __builtin_amdgcn_mfma_f32_16x16x32_bf16(a,b,c,0,0,0)

static constexpr int S_ = 2048;
static constexpr size_t QKV_ELEMS = 3145728;   // 2*12*2048*64 == 4096*768
static constexpr size_t W_ELEMS   = 589824;    // 768*768
static constexpr size_t OUT0_ELEMS = 3145728;

__device__ __forceinline__ unsigned short f2bf(float f) {
    union { float f; unsigned u; } v; v.f = f;
    unsigned u = v.u;
    u += 0x7fffu + ((u >> 16) & 1u);   // RNE
    return (unsigned short)(u >> 16);
}

__device__ __forceinline__ void gload_lds16(const short* g, short* l) {
    __builtin_amdgcn_global_load_lds((const __attribute__((address_space(1))) void*)g,
                                     (__attribute__((address_space(3))) void*)l,
                                     16, 0, 0);
}

// ---------------------------------------------------------------------------
// fp32 -> bf16 conversion, 7 tensors in one launch (z picks tensor).
// Also zeroes the attn work-queue counter (stream-ordered before attn).
// ---------------------------------------------------------------------------
struct CvtP { const float* s[7]; unsigned short* d[7]; int n[7]; int* ctr; };

__global__ __launch_bounds__(256)
void cvt_all(CvtP p)
{
    const int z = blockIdx.z;
    if (z == 0 && blockIdx.x == 0 && threadIdx.x == 0) *p.ctr = 0;
    const int i = (blockIdx.x * 256 + threadIdx.x) * 8;
    if (i >= p.n[z]) return;
    const float* s = p.s[z] + i;
    float4 a = *(const float4*)s, b = *(const float4*)(s + 4);
    uint4 u;
    u.x = (unsigned)f2bf(a.x) | ((unsigned)f2bf(a.y) << 16);
    u.y = (unsigned)f2bf(a.z) | ((unsigned)f2bf(a.w) << 16);
    u.z = (unsigned)f2bf(b.x) | ((unsigned)f2bf(b.y) << 16);
    u.w = (unsigned)f2bf(b.z) | ((unsigned)f2bf(b.w) << 16);
    *(uint4*)(p.d[z] + i) = u;
}

// ---------------------------------------------------------------------------
// bf16 MFMA GEMM: C = A[4096x768] @ W^T[768x768] + bias, 128x128 tile, BK=32.
// m97 structure: global -> LDS via global_load_lds_dwordx4 (linear [128][32]
// LDS, no pad; wave-uniform base + lane*16 dest). Frag math unchanged.
// mode 0: headed bf16 [bh][s][64] (Q/K); mode 1: transposed bf16 [bh][dk][2048]
// (V, ushort4-packed stores along s); mode 2: flat fp32 [4096][768] (O-proj).
// ---------------------------------------------------------------------------
struct GemmP {
    const short* A[3]; const short* W[3]; const float* bias[3];
    void* C[3]; float scale[3]; int mode[3];
};

__global__ __launch_bounds__(256)
void gemm_bf16(GemmP p)
{
    const int z = blockIdx.z;
    const short* __restrict__ A = p.A[z];
    const short* __restrict__ W = p.W[z];
    const float* __restrict__ bias = p.bias[z];
    const float scale = p.scale[z];
    const int mode = p.mode[z];

    __shared__ short As[128 * 32];
    __shared__ short Bs[128 * 32];

    const int t = threadIdx.x;
    const int m0 = blockIdx.y * 128, n0 = blockIdx.x * 128;
    const int w = t >> 6, lane = t & 63, li = lane & 15, qd = lane >> 4;
    const int wm = (w & 1) * 64, wn = (w >> 1) * 64;

    f4_t acc[4][4];
    #pragma unroll
    for (int i = 0; i < 4; ++i)
        #pragma unroll
        for (int j = 0; j < 4; ++j)
            #pragma unroll
            for (int r = 0; r < 4; ++r) acc[i][j][r] = 0.f;

    for (int k0 = 0; k0 < 768; k0 += 32) {
        #pragma unroll
        for (int e = 0; e < 2; ++e) {
            const int ch = t + e * 256;            // 0..511 chunk id (16B each)
            const int r = ch >> 2, c = (ch & 3) << 3;
            gload_lds16(&A[(size_t)(m0 + r) * 768 + k0 + c], &As[ch << 3]);
            gload_lds16(&W[(size_t)(n0 + r) * 768 + k0 + c], &Bs[ch << 3]);
        }
        __syncthreads();                            // drains vmcnt before barrier
        bf8_t af[4], bf[4];
        #pragma unroll
        for (int i = 0; i < 4; ++i) af[i] = *(const bf8_t*)&As[(wm + i * 16 + li) * 32 + qd * 8];
        #pragma unroll
        for (int j = 0; j < 4; ++j) bf[j] = *(const bf8_t*)&Bs[(wn + j * 16 + li) * 32 + qd * 8];
        #pragma unroll
        for (int i = 0; i < 4; ++i)
            #pragma unroll
            for (int j = 0; j < 4; ++j)
                acc[i][j] = MFMA(af[i], bf[j], acc[i][j]);
        __syncthreads();
    }

    #pragma unroll
    for (int i = 0; i < 4; ++i) {
        const int row = m0 + wm + i * 16 + qd * 4;
        #pragma unroll
        for (int j = 0; j < 4; ++j) {
            const int col = n0 + wn + j * 16 + li;
            const float bv = bias[col];
            float vals[4];
            #pragma unroll
            for (int r = 0; r < 4; ++r) vals[r] = (acc[i][j][r] + bv) * scale;
            if (mode == 0) {
                #pragma unroll
                for (int r = 0; r < 4; ++r) {
                    const int rr = row + r;
                    int bh = (rr >> 11) * 12 + (col >> 6);
                    ((unsigned short*)p.C[z])[((size_t)bh * 2048 + (rr & 2047)) * 64 + (col & 63)] = f2bf(vals[r]);
                }
            } else if (mode == 1) {
                int bh = (row >> 11) * 12 + (col >> 6);
                ushort4 u;
                u.x = f2bf(vals[0]); u.y = f2bf(vals[1]);
                u.z = f2bf(vals[2]); u.w = f2bf(vals[3]);
                *(ushort4*)&((unsigned short*)p.C[z])[(size_t)(bh * 64 + (col & 63)) * 2048 + (row & 2047)] = u;
            } else {
                #pragma unroll
                for (int r = 0; r < 4; ++r)
                    ((float*)p.C[z])[(size_t)(row + r) * 768 + col] = vals[r];
            }
        }
    }
}

// ---------------------------------------------------------------------------
// Fused attention, 4 waves (256 threads) per 64-row q-tile, LDS-staged K/V.
// PERSISTENT blocks + dynamic work queue: 768 items (bh, qt) ordered
// longest-causal-range first (LPT), pulled via atomicAdd. Fixes the CU-level
// imbalance of the static 32x24 grid (same-qt blocks landed on the same CU,
// making the kernel ~1.9x the balanced ideal).
// Per item: double-buffered LDS K (pass 1) and K+V (pass 2), 16B-chunk XOR
// swizzle (chunk ^= row&7) for conflict-free ds_read_b128.
// Pass 1: per-lane online (m,l); one shuffle-merge at the end.
// Pass 2: recompute S, write normalized fp32 attn, P->bf16 via per-wave
// swizzled LDS (in-wave, no barrier), O += P*V (V^T frags from LDS).
// LDS total = 16KB K + 16KB V + 8KB Ps = 40KB -> 4 blocks/CU max.
// ---------------------------------------------------------------------------
__global__ __launch_bounds__(256)
void attn_fused(const short* __restrict__ Qb, const short* __restrict__ Kb,
                const short* __restrict__ Vt, float* __restrict__ attn,
                unsigned short* __restrict__ AO, int* __restrict__ ctr)
{
    __shared__ short Ks[2][4096];           // K tile  [64 rows][8 chunks of 8 bf16], swizzled
    __shared__ short Vs[2][4096];           // V^T tile, same layout
    __shared__ short Ps[4][1024];           // per-wave P tile [16][8 chunks], swizzled
    __shared__ int sh_j;

    const int t = threadIdx.x;
    const int ws = t >> 6;                  // wave strip 0..3
    const int lane = t & 63;
    const int li = lane & 15, qd = lane >> 4;
    const int r0 = t >> 3, c0 = t & 7;           // staging: row 0..31, 16B chunk 0..7
    const int csw = ((c0 ^ (r0 & 7)) << 3);      // swizzled chunk offset (shorts)
    const int lsw = li & 7;                      // read-side row swizzle key
    const float NEG = -1e30f;

    for (;;) {
        if (t == 0) sh_j = atomicAdd(ctr, 1);
        __syncthreads();                    // broadcast + prev-item LDS drain
        const int j = sh_j;
        if (j >= 768) return;
        const int qt = 31 - (j / 24);       // longest k-range first (LPT)
        const int bh = j % 24;

        const int q0 = qt * 64 + ws * 16;
        const short* Qp = Qb + ((size_t)bh * 2048 + q0 + li) * 64;
        const bf8_t qf0 = *(const bf8_t*)&Qp[qd * 8];
        const bf8_t qf1 = *(const bf8_t*)&Qp[32 + qd * 8];

        const short* Kbh = Kb + (size_t)bh * 2048 * 64;
        const short* Vbh = Vt + (size_t)bh * 64 * 2048;
        float* attnp = attn + (size_t)bh * 2048 * 2048;
        short* Psw = Ps[ws];

        float m_[4] = {NEG, NEG, NEG, NEG}, l_[4] = {0.f, 0.f, 0.f, 0.f};

        // ---------------- pass 1: per-lane online stats ----------------
        {
            float4 ka = *(const float4*)&Kbh[(size_t)r0 * 64 + (c0 << 3)];
            float4 kb_ = *(const float4*)&Kbh[(size_t)(r0 + 32) * 64 + (c0 << 3)];
            *(float4*)&Ks[0][r0 * 64 + csw] = ka;
            *(float4*)&Ks[0][(r0 + 32) * 64 + csw] = kb_;
            int cur = 0;
            for (int kt = 0; kt <= qt; ++kt) {
                float4 na, nb;
                if (kt < qt) {
                    na = *(const float4*)&Kbh[(size_t)((kt + 1) * 64 + r0) * 64 + (c0 << 3)];
                    nb = *(const float4*)&Kbh[(size_t)((kt + 1) * 64 + r0 + 32) * 64 + (c0 << 3)];
                }
                __syncthreads();                    // buf[cur] ready for all waves
                const short* Kc = Ks[cur];
                bf8_t kf0[4], kf1[4];
                #pragma unroll
                for (int sub = 0; sub < 4; ++sub) {
                    const int kr = sub * 16 + li;
                    kf0[sub] = *(const bf8_t*)&Kc[kr * 64 + ((qd ^ lsw) << 3)];
                    kf1[sub] = *(const bf8_t*)&Kc[kr * 64 + (((4 + qd) ^ lsw) << 3)];
                }
                f4_t c[4];
                __builtin_amdgcn_s_setprio(1);
                #pragma unroll
                for (int sub = 0; sub < 4; ++sub) {
                    f4_t z; z[0] = z[1] = z[2] = z[3] = 0.f;
                    z = MFMA(qf0, kf0[sub], z);
                    z = MFMA(qf1, kf1[sub], z);
                    c[sub] = z;
                }
                __builtin_amdgcn_s_setprio(0);
                if (kt == qt) {
                    #pragma unroll
                    for (int sub = 0; sub < 4; ++sub)
                        #pragma unroll
                        for (int r = 0; r < 4; ++r)
                            if (sub * 16 + li > ws * 16 + qd * 4 + r) c[sub][r] = NEG;
                }
                #pragma unroll
                for (int r = 0; r < 4; ++r) {
                    float tm = fmaxf(fmaxf(c[0][r], c[1][r]), fmaxf(c[2][r], c[3][r]));
                    float nm = fmaxf(m_[r], tm);
                    float s = __expf(c[0][r] - nm) + __expf(c[1][r] - nm)
                            + __expf(c[2][r] - nm) + __expf(c[3][r] - nm);
                    l_[r] = l_[r] * __expf(m_[r] - nm) + s;
                    m_[r] = nm;
                }
                if (kt < qt) {                      // write-late into the other buffer
                    *(float4*)&Ks[cur ^ 1][r0 * 64 + csw] = na;
                    *(float4*)&Ks[cur ^ 1][(r0 + 32) * 64 + csw] = nb;
                    cur ^= 1;
                }
            }
        }

        // ---------------- cross-lane merge (once, per wave) ----------------
        float invl[4];
        #pragma unroll
        for (int r = 0; r < 4; ++r) {
            float mg = m_[r];
            mg = fmaxf(mg, __shfl_xor(mg, 1, 64));
            mg = fmaxf(mg, __shfl_xor(mg, 2, 64));
            mg = fmaxf(mg, __shfl_xor(mg, 4, 64));
            mg = fmaxf(mg, __shfl_xor(mg, 8, 64));
            float lg = l_[r] * __expf(m_[r] - mg);
            lg += __shfl_xor(lg, 1, 64);
            lg += __shfl_xor(lg, 2, 64);
            lg += __shfl_xor(lg, 4, 64);
            lg += __shfl_xor(lg, 8, 64);
            m_[r] = mg;
            invl[r] = 1.f / lg;
        }

        // ---------------- pass 2: P store + O accumulate ----------------
        f4_t o[4];
        #pragma unroll
        for (int d = 0; d < 4; ++d)
            #pragma unroll
            for (int r = 0; r < 4; ++r) o[d][r] = 0.f;

        {
            float4 ka = *(const float4*)&Kbh[(size_t)r0 * 64 + (c0 << 3)];
            float4 kb_ = *(const float4*)&Kbh[(size_t)(r0 + 32) * 64 + (c0 << 3)];
            float4 va = *(const float4*)&Vbh[(size_t)r0 * 2048 + (c0 << 3)];
            float4 vc_ = *(const float4*)&Vbh[(size_t)(r0 + 32) * 2048 + (c0 << 3)];
            __syncthreads();                        // pass-1 LDS reads complete
            *(float4*)&Ks[0][r0 * 64 + csw] = ka;
            *(float4*)&Ks[0][(r0 + 32) * 64 + csw] = kb_;
            *(float4*)&Vs[0][r0 * 64 + csw] = va;
            *(float4*)&Vs[0][(r0 + 32) * 64 + csw] = vc_;
            int cur = 0;
            for (int kt = 0; kt <= qt; ++kt) {
                float4 nka, nkb, nva, nvb;
                if (kt < qt) {                      // issue-early
                    nka = *(const float4*)&Kbh[(size_t)((kt + 1) * 64 + r0) * 64 + (c0 << 3)];
                    nkb = *(const float4*)&Kbh[(size_t)((kt + 1) * 64 + r0 + 32) * 64 + (c0 << 3)];
                    nva = *(const float4*)&Vbh[(size_t)r0 * 2048 + (kt + 1) * 64 + (c0 << 3)];
                    nvb = *(const float4*)&Vbh[(size_t)(r0 + 32) * 2048 + (kt + 1) * 64 + (c0 << 3)];
                }
                __syncthreads();
                const short* Kc = Ks[cur];
                const short* Vc = Vs[cur];
                bf8_t kf0[4], kf1[4];
                #pragma unroll
                for (int sub = 0; sub < 4; ++sub) {
                    const int kr = sub * 16 + li;
                    kf0[sub] = *(const bf8_t*)&Kc[kr * 64 + ((qd ^ lsw) << 3)];
                    kf1[sub] = *(const bf8_t*)&Kc[kr * 64 + (((4 + qd) ^ lsw) << 3)];
                }
                f4_t c[4];
                __builtin_amdgcn_s_setprio(1);
                #pragma unroll
                for (int sub = 0; sub < 4; ++sub) {
                    f4_t z; z[0] = z[1] = z[2] = z[3] = 0.f;
                    z = MFMA(qf0, kf0[sub], z);
                    z = MFMA(qf1, kf1[sub], z);
                    c[sub] = z;
                }
                __builtin_amdgcn_s_setprio(0);
                if (kt == qt) {
                    #pragma unroll
                    for (int sub = 0; sub < 4; ++sub)
                        #pragma unroll
                        for (int r = 0; r < 4; ++r)
                            if (sub * 16 + li > ws * 16 + qd * 4 + r) c[sub][r] = NEG;
                }
                #pragma unroll
                for (int sub = 0; sub < 4; ++sub)
                    #pragma unroll
                    for (int r = 0; r < 4; ++r) {
                        const float pe = __expf(c[sub][r] - m_[r]) * invl[r];
                        attnp[(size_t)(q0 + qd * 4 + r) * 2048 + kt * 64 + sub * 16 + li] = pe;
                        const int prow = qd * 4 + r;
                        const int pcol = sub * 16 + li;
                        Psw[prow * 64 + (((pcol >> 3) ^ (prow & 7)) << 3) + (pcol & 7)] = (short)f2bf(pe);
                    }
                __builtin_amdgcn_s_setprio(1);
                #pragma unroll
                for (int h = 0; h < 2; ++h) {
                    bf8_t pa = *(const bf8_t*)&Psw[li * 64 + (((h * 4 + qd) ^ lsw) << 3)];
                    #pragma unroll
                    for (int d = 0; d < 4; ++d) {
                        bf8_t vf = *(const bf8_t*)&Vc[(d * 16 + li) * 64 + (((h * 4 + qd) ^ lsw) << 3)];
                        o[d] = MFMA(pa, vf, o[d]);
                    }
                }
                __builtin_amdgcn_s_setprio(0);
                if (kt < qt) {                      // write-late
                    *(float4*)&Ks[cur ^ 1][r0 * 64 + csw] = nka;
                    *(float4*)&Ks[cur ^ 1][(r0 + 32) * 64 + csw] = nkb;
                    *(float4*)&Vs[cur ^ 1][r0 * 64 + csw] = nva;
                    *(float4*)&Vs[cur ^ 1][(r0 + 32) * 64 + csw] = nvb;
                    cur ^= 1;
                }
            }
        }

        // zero-fill strictly-above-diagonal region for this wave's 16 rows
        const int w4 = (31 - qt) * 16;   // float4s per row
        const float4 z4 = make_float4(0.f, 0.f, 0.f, 0.f);
        for (int r = 0; r < 16; ++r) {
            float* rp = &attnp[(size_t)(q0 + r) * 2048 + (qt + 1) * 64];
            for (int cc = lane; cc < w4; cc += 64)
                *(float4*)&rp[cc * 4] = z4;
        }

        // O epilogue -> AO bf16 [4096][768]
        const int b = bh / 12, h_ = bh % 12;
        #pragma unroll
        for (int d = 0; d < 4; ++d)
            #pragma unroll
            for (int r = 0; r < 4; ++r)
                AO[(size_t)(b * 2048 + q0 + qd * 4 + r) * 768 + h_ * 64 + d * 16 + li] = f2bf(o[d][r]);
    }
}

// ---------------------------------------------------------------------------
// LayerNorm: out = LN(resid + proj) * gamma + beta, one block per 768-row.
// ---------------------------------------------------------------------------
__global__ __launch_bounds__(256)
void ln_kernel(const float* __restrict__ resid, const float* __restrict__ proj,
               const float* __restrict__ gamma, const float* __restrict__ beta,
               float* __restrict__ out)
{
    __shared__ float red[4];
    const int row = blockIdx.x, t = threadIdx.x;
    const size_t base = (size_t)row * 768;
    float x[3];
    float s = 0.f;
    #pragma unroll
    for (int e = 0; e < 3; ++e) {
        int j = t + e * 256;
        x[e] = resid[base + j] + proj[base + j];
        s += x[e];
    }
    #pragma unroll
    for (int off = 1; off < 64; off <<= 1) s += __shfl_xor(s, off, 64);
    if ((t & 63) == 0) red[t >> 6] = s;
    __syncthreads();
    s = red[0] + red[1] + red[2] + red[3];
    const float mu = s * (1.f / 768.f);
    float vs = 0.f;
    #pragma unroll
    for (int e = 0; e < 3; ++e) { float d = x[e] - mu; vs += d * d; }
    __syncthreads();
    #pragma unroll
    for (int off = 1; off < 64; off <<= 1) vs += __shfl_xor(vs, off, 64);
    if ((t & 63) == 0) red[t >> 6] = vs;
    __syncthreads();
    vs = red[0] + red[1] + red[2] + red[3];
    const float inv = rsqrtf(vs * (1.f / 768.f) + 1e-5f);
    #pragma unroll
    for (int e = 0; e < 3; ++e) {
        int j = t + e * 256;
        out[base + j] = (x[e] - mu) * inv * gamma[j] + beta[j];
    }
}

extern "C" void kernel_launch(void* const* d_in, const int* in_sizes, int n_in,
                              void* d_out, int out_size, void* d_ws, size_t ws_size,
                              hipStream_t stream)
{
    const float* q     = (const float*)d_in[0];
    const float* k     = (const float*)d_in[1];
    const float* v     = (const float*)d_in[2];
    const float* Wq    = (const float*)d_in[4];
    const float* bq    = (const float*)d_in[5];
    const float* Wk    = (const float*)d_in[6];
    const float* bk    = (const float*)d_in[7];
    const float* Wv    = (const float*)d_in[8];
    const float* bv    = (const float*)d_in[9];
    const float* Wo    = (const float*)d_in[10];
    const float* bo    = (const float*)d_in[11];
    const float* gamma = (const float*)d_in[12];
    const float* beta  = (const float*)d_in[13];

    float* out  = (float*)d_out;
    float* attn = out + OUT0_ELEMS;

    short* qc  = (short*)d_ws;
    short* kc  = qc + QKV_ELEMS;
    short* vc  = kc + QKV_ELEMS;
    short* wqc = vc + QKV_ELEMS;
    short* wkc = wqc + W_ELEMS;
    short* wvc = wkc + W_ELEMS;
    short* woc = wvc + W_ELEMS;
    short* Qb  = woc + W_ELEMS;
    short* Kb  = Qb + QKV_ELEMS;
    short* Vt  = Kb + QKV_ELEMS;
    short* AO  = Vt + QKV_ELEMS;
    float* P   = (float*)(AO + QKV_ELEMS);
    int*   ctr = (int*)(P + OUT0_ELEMS);

    CvtP cp;
    cp.s[0] = q;  cp.d[0] = (unsigned short*)qc;  cp.n[0] = (int)QKV_ELEMS;
    cp.s[1] = k;  cp.d[1] = (unsigned short*)kc;  cp.n[1] = (int)QKV_ELEMS;
    cp.s[2] = v;  cp.d[2] = (unsigned short*)vc;  cp.n[2] = (int)QKV_ELEMS;
    cp.s[3] = Wq; cp.d[3] = (unsigned short*)wqc; cp.n[3] = (int)W_ELEMS;
    cp.s[4] = Wk; cp.d[4] = (unsigned short*)wkc; cp.n[4] = (int)W_ELEMS;
    cp.s[5] = Wv; cp.d[5] = (unsigned short*)wvc; cp.n[5] = (int)W_ELEMS;
    cp.s[6] = Wo; cp.d[6] = (unsigned short*)woc; cp.n[6] = (int)W_ELEMS;
    cp.ctr = ctr;
    cvt_all<<<dim3(1536, 1, 7), 256, 0, stream>>>(cp);

    GemmP gp;
    gp.A[0] = qc; gp.W[0] = wqc; gp.bias[0] = bq; gp.C[0] = Qb; gp.scale[0] = 0.125f; gp.mode[0] = 0;
    gp.A[1] = kc; gp.W[1] = wkc; gp.bias[1] = bk; gp.C[1] = Kb; gp.scale[1] = 1.f;    gp.mode[1] = 0;
    gp.A[2] = vc; gp.W[2] = wvc; gp.bias[2] = bv; gp.C[2] = Vt; gp.scale[2] = 1.f;    gp.mode[2] = 1;
    gemm_bf16<<<dim3(6, 32, 3), 256, 0, stream>>>(gp);

    attn_fused<<<dim3(640), 256, 0, stream>>>(Qb, Kb, Vt, attn, (unsigned short*)AO, ctr);

    GemmP gp2;
    gp2.A[0] = AO; gp2.W[0] = woc; gp2.bias[0] = bo; gp2.C[0] = P; gp2.scale[0] = 1.f; gp2.mode[0] = 2;
    gp2.A[1] = gp2.A[2] = AO; gp2.W[1] = gp2.W[2] = woc; gp2.bias[1] = gp2.bias[2] = bo;
    gp2.C[1] = gp2.C[2] = P; gp2.scale[1] = gp2.scale[2] = 1.f; gp2.mode[1] = gp2.mode[2] = 2;
    gemm_bf16<<<dim3(6, 32, 1), 256, 0, stream>>>(gp2);

    ln_kernel<<<dim3(4096), 256, 0, stream>>>(q, P, gamma, beta, out);
}

// Round 3
// 569.440 us; speedup vs baseline: 1.0716x; 1.0716x over previous
//
#include <hip/hip_runtime.h>
#include <math.h>

typedef __attribute__((ext_vector_type(8))) short bf8_t;   // 8 bf16 in 4 VGPRs
typedef __attribute__((ext_vector_type(4))) float f4_t;    // MFMA C/D frag

#define MFMA(a,b,c) __builtin_amdgcn_mfma_f32_16x16x32_bf16(a,b,c,0,0,0)

static constexpr int S_ = 2048;
static constexpr size_t QKV_ELEMS = 3145728;   // 2*12*2048*64 == 4096*768
static constexpr size_t W_ELEMS   = 589824;    // 768*768
static constexpr size_t OUT0_ELEMS = 3145728;

__device__ __forceinline__ unsigned short f2bf(float f) {
    union { float f; unsigned u; } v; v.f = f;
    unsigned u = v.u;
    u += 0x7fffu + ((u >> 16) & 1u);   // RNE
    return (unsigned short)(u >> 16);
}

__device__ __forceinline__ void gload_lds16(const short* g, short* l) {
    __builtin_amdgcn_global_load_lds((const __attribute__((address_space(1))) void*)g,
                                     (__attribute__((address_space(3))) void*)l,
                                     16, 0, 0);
}

// ---------------------------------------------------------------------------
// fp32 -> bf16 conversion, 7 tensors in one launch (z picks tensor)
// ---------------------------------------------------------------------------
struct CvtP { const float* s[7]; unsigned short* d[7]; int n[7]; };

__global__ __launch_bounds__(256)
void cvt_all(CvtP p)
{
    const int z = blockIdx.z;
    const int i = (blockIdx.x * 256 + threadIdx.x) * 8;
    if (i >= p.n[z]) return;
    const float* s = p.s[z] + i;
    float4 a = *(const float4*)s, b = *(const float4*)(s + 4);
    uint4 u;
    u.x = (unsigned)f2bf(a.x) | ((unsigned)f2bf(a.y) << 16);
    u.y = (unsigned)f2bf(a.z) | ((unsigned)f2bf(a.w) << 16);
    u.z = (unsigned)f2bf(b.x) | ((unsigned)f2bf(b.y) << 16);
    u.w = (unsigned)f2bf(b.z) | ((unsigned)f2bf(b.w) << 16);
    *(uint4*)(p.d[z] + i) = u;
}

// ---------------------------------------------------------------------------
// bf16 MFMA GEMM: C = A[4096x768] @ W^T[768x768] + bias, 128x128 tile, BK=32.
// m97 structure: global -> LDS via global_load_lds_dwordx4 (linear [128][32]
// LDS, no pad; wave-uniform base + lane*16 dest). Frag math unchanged.
// mode 0: headed bf16 [bh][s][64] (Q/K); mode 1: transposed bf16 [bh][dk][2048]
// (V, ushort4-packed stores along s); mode 2: flat fp32 [4096][768] (O-proj).
// ---------------------------------------------------------------------------
struct GemmP {
    const short* A[3]; const short* W[3]; const float* bias[3];
    void* C[3]; float scale[3]; int mode[3];
};

__global__ __launch_bounds__(256)
void gemm_bf16(GemmP p)
{
    const int z = blockIdx.z;
    const short* __restrict__ A = p.A[z];
    const short* __restrict__ W = p.W[z];
    const float* __restrict__ bias = p.bias[z];
    const float scale = p.scale[z];
    const int mode = p.mode[z];

    __shared__ short As[128 * 32];
    __shared__ short Bs[128 * 32];

    const int t = threadIdx.x;
    const int m0 = blockIdx.y * 128, n0 = blockIdx.x * 128;
    const int w = t >> 6, lane = t & 63, li = lane & 15, qd = lane >> 4;
    const int wm = (w & 1) * 64, wn = (w >> 1) * 64;

    f4_t acc[4][4];
    #pragma unroll
    for (int i = 0; i < 4; ++i)
        #pragma unroll
        for (int j = 0; j < 4; ++j)
            #pragma unroll
            for (int r = 0; r < 4; ++r) acc[i][j][r] = 0.f;

    for (int k0 = 0; k0 < 768; k0 += 32) {
        #pragma unroll
        for (int e = 0; e < 2; ++e) {
            const int ch = t + e * 256;            // 0..511 chunk id (16B each)
            const int r = ch >> 2, c = (ch & 3) << 3;
            gload_lds16(&A[(size_t)(m0 + r) * 768 + k0 + c], &As[ch << 3]);
            gload_lds16(&W[(size_t)(n0 + r) * 768 + k0 + c], &Bs[ch << 3]);
        }
        __syncthreads();                            // drains vmcnt before barrier
        bf8_t af[4], bf[4];
        #pragma unroll
        for (int i = 0; i < 4; ++i) af[i] = *(const bf8_t*)&As[(wm + i * 16 + li) * 32 + qd * 8];
        #pragma unroll
        for (int j = 0; j < 4; ++j) bf[j] = *(const bf8_t*)&Bs[(wn + j * 16 + li) * 32 + qd * 8];
        #pragma unroll
        for (int i = 0; i < 4; ++i)
            #pragma unroll
            for (int j = 0; j < 4; ++j)
                acc[i][j] = MFMA(af[i], bf[j], acc[i][j]);
        __syncthreads();
    }

    #pragma unroll
    for (int i = 0; i < 4; ++i) {
        const int row = m0 + wm + i * 16 + qd * 4;
        #pragma unroll
        for (int j = 0; j < 4; ++j) {
            const int col = n0 + wn + j * 16 + li;
            const float bv = bias[col];
            float vals[4];
            #pragma unroll
            for (int r = 0; r < 4; ++r) vals[r] = (acc[i][j][r] + bv) * scale;
            if (mode == 0) {
                #pragma unroll
                for (int r = 0; r < 4; ++r) {
                    const int rr = row + r;
                    int bh = (rr >> 11) * 12 + (col >> 6);
                    ((unsigned short*)p.C[z])[((size_t)bh * 2048 + (rr & 2047)) * 64 + (col & 63)] = f2bf(vals[r]);
                }
            } else if (mode == 1) {
                int bh = (row >> 11) * 12 + (col >> 6);
                ushort4 u;
                u.x = f2bf(vals[0]); u.y = f2bf(vals[1]);
                u.z = f2bf(vals[2]); u.w = f2bf(vals[3]);
                *(ushort4*)&((unsigned short*)p.C[z])[(size_t)(bh * 64 + (col & 63)) * 2048 + (row & 2047)] = u;
            } else {
                #pragma unroll
                for (int r = 0; r < 4; ++r)
                    ((float*)p.C[z])[(size_t)(row + r) * 768 + col] = vals[r];
            }
        }
    }
}

// ---------------------------------------------------------------------------
// Fused attention, 4 waves (256 threads) per 64-row q-tile, LDS-staged K/V.
// STATIC COMPLEMENTARY SCHEDULE: 768 blocks, all resident (3/CU at 40KB LDS).
// The runtime places blocks B, B+256, B+512 on the same CU (id round-robin),
// so we map CU-slot s = B&255 to cost-sorted items {s, 511-s, 512+s}: per-CU
// work = 45..54 tile-steps vs ideal 49.5 (1.09x imbalance, vs 1.94x for the
// naive grid). No atomics, no queue. setprio removed (hurts lockstep waves).
// Per item: double-buffered LDS K (pass 1) and K+V (pass 2), 16B-chunk XOR
// swizzle (chunk ^= row&7) for conflict-free ds_read_b128.
// Pass 1: per-lane online (m,l); one shuffle-merge at the end.
// Pass 2: recompute S, write normalized fp32 attn, P->bf16 via per-wave
// swizzled LDS (in-wave, no barrier), O += P*V (V^T frags from LDS).
// ---------------------------------------------------------------------------
__global__ __launch_bounds__(256)
void attn_fused(const short* __restrict__ Qb, const short* __restrict__ Kb,
                const short* __restrict__ Vt, float* __restrict__ attn,
                unsigned short* __restrict__ AO)
{
    __shared__ short Ks[2][4096];           // K tile  [64 rows][8 chunks of 8 bf16], swizzled
    __shared__ short Vs[2][4096];           // V^T tile, same layout
    __shared__ short Ps[4][1024];           // per-wave P tile [16][8 chunks], swizzled

    const int B = blockIdx.x;
    const int s_ = B & 255, rr_ = B >> 8;
    const int item = (rr_ == 0) ? s_ : (rr_ == 1) ? (511 - s_) : (512 + s_);
    const int qt = 31 - (item / 24);        // cost-sorted: item 0 is longest
    const int bh = item % 24;

    const int t = threadIdx.x;
    const int ws = t >> 6;                  // wave strip 0..3
    const int lane = t & 63;
    const int li = lane & 15, qd = lane >> 4;
    const int r0 = t >> 3, c0 = t & 7;           // staging: row 0..31, 16B chunk 0..7
    const int csw = ((c0 ^ (r0 & 7)) << 3);      // swizzled chunk offset (shorts)
    const int lsw = li & 7;                      // read-side row swizzle key
    const float NEG = -1e30f;

    const int q0 = qt * 64 + ws * 16;
    const short* Qp = Qb + ((size_t)bh * 2048 + q0 + li) * 64;
    const bf8_t qf0 = *(const bf8_t*)&Qp[qd * 8];
    const bf8_t qf1 = *(const bf8_t*)&Qp[32 + qd * 8];

    const short* Kbh = Kb + (size_t)bh * 2048 * 64;
    const short* Vbh = Vt + (size_t)bh * 64 * 2048;
    float* attnp = attn + (size_t)bh * 2048 * 2048;
    short* Psw = Ps[ws];

    float m_[4] = {NEG, NEG, NEG, NEG}, l_[4] = {0.f, 0.f, 0.f, 0.f};

    // ---------------- pass 1: per-lane online stats ----------------
    {
        float4 ka = *(const float4*)&Kbh[(size_t)r0 * 64 + (c0 << 3)];
        float4 kb_ = *(const float4*)&Kbh[(size_t)(r0 + 32) * 64 + (c0 << 3)];
        *(float4*)&Ks[0][r0 * 64 + csw] = ka;
        *(float4*)&Ks[0][(r0 + 32) * 64 + csw] = kb_;
        int cur = 0;
        for (int kt = 0; kt <= qt; ++kt) {
            float4 na, nb;
            if (kt < qt) {
                na = *(const float4*)&Kbh[(size_t)((kt + 1) * 64 + r0) * 64 + (c0 << 3)];
                nb = *(const float4*)&Kbh[(size_t)((kt + 1) * 64 + r0 + 32) * 64 + (c0 << 3)];
            }
            __syncthreads();                    // buf[cur] ready for all waves
            const short* Kc = Ks[cur];
            bf8_t kf0[4], kf1[4];
            #pragma unroll
            for (int sub = 0; sub < 4; ++sub) {
                const int kr = sub * 16 + li;
                kf0[sub] = *(const bf8_t*)&Kc[kr * 64 + ((qd ^ lsw) << 3)];
                kf1[sub] = *(const bf8_t*)&Kc[kr * 64 + (((4 + qd) ^ lsw) << 3)];
            }
            f4_t c[4];
            #pragma unroll
            for (int sub = 0; sub < 4; ++sub) {
                f4_t z; z[0] = z[1] = z[2] = z[3] = 0.f;
                z = MFMA(qf0, kf0[sub], z);
                z = MFMA(qf1, kf1[sub], z);
                c[sub] = z;
            }
            if (kt == qt) {
                #pragma unroll
                for (int sub = 0; sub < 4; ++sub)
                    #pragma unroll
                    for (int r = 0; r < 4; ++r)
                        if (sub * 16 + li > ws * 16 + qd * 4 + r) c[sub][r] = NEG;
            }
            #pragma unroll
            for (int r = 0; r < 4; ++r) {
                float tm = fmaxf(fmaxf(c[0][r], c[1][r]), fmaxf(c[2][r], c[3][r]));
                float nm = fmaxf(m_[r], tm);
                float s = __expf(c[0][r] - nm) + __expf(c[1][r] - nm)
                        + __expf(c[2][r] - nm) + __expf(c[3][r] - nm);
                l_[r] = l_[r] * __expf(m_[r] - nm) + s;
                m_[r] = nm;
            }
            if (kt < qt) {                      // write-late into the other buffer
                *(float4*)&Ks[cur ^ 1][r0 * 64 + csw] = na;
                *(float4*)&Ks[cur ^ 1][(r0 + 32) * 64 + csw] = nb;
                cur ^= 1;
            }
        }
    }

    // ---------------- cross-lane merge (once, per wave) ----------------
    float invl[4];
    #pragma unroll
    for (int r = 0; r < 4; ++r) {
        float mg = m_[r];
        mg = fmaxf(mg, __shfl_xor(mg, 1, 64));
        mg = fmaxf(mg, __shfl_xor(mg, 2, 64));
        mg = fmaxf(mg, __shfl_xor(mg, 4, 64));
        mg = fmaxf(mg, __shfl_xor(mg, 8, 64));
        float lg = l_[r] * __expf(m_[r] - mg);
        lg += __shfl_xor(lg, 1, 64);
        lg += __shfl_xor(lg, 2, 64);
        lg += __shfl_xor(lg, 4, 64);
        lg += __shfl_xor(lg, 8, 64);
        m_[r] = mg;
        invl[r] = 1.f / lg;
    }

    // ---------------- pass 2: P store + O accumulate ----------------
    f4_t o[4];
    #pragma unroll
    for (int d = 0; d < 4; ++d)
        #pragma unroll
        for (int r = 0; r < 4; ++r) o[d][r] = 0.f;

    {
        float4 ka = *(const float4*)&Kbh[(size_t)r0 * 64 + (c0 << 3)];
        float4 kb_ = *(const float4*)&Kbh[(size_t)(r0 + 32) * 64 + (c0 << 3)];
        float4 va = *(const float4*)&Vbh[(size_t)r0 * 2048 + (c0 << 3)];
        float4 vc_ = *(const float4*)&Vbh[(size_t)(r0 + 32) * 2048 + (c0 << 3)];
        __syncthreads();                        // pass-1 LDS reads complete
        *(float4*)&Ks[0][r0 * 64 + csw] = ka;
        *(float4*)&Ks[0][(r0 + 32) * 64 + csw] = kb_;
        *(float4*)&Vs[0][r0 * 64 + csw] = va;
        *(float4*)&Vs[0][(r0 + 32) * 64 + csw] = vc_;
        int cur = 0;
        for (int kt = 0; kt <= qt; ++kt) {
            float4 nka, nkb, nva, nvb;
            if (kt < qt) {                      // issue-early
                nka = *(const float4*)&Kbh[(size_t)((kt + 1) * 64 + r0) * 64 + (c0 << 3)];
                nkb = *(const float4*)&Kbh[(size_t)((kt + 1) * 64 + r0 + 32) * 64 + (c0 << 3)];
                nva = *(const float4*)&Vbh[(size_t)r0 * 2048 + (kt + 1) * 64 + (c0 << 3)];
                nvb = *(const float4*)&Vbh[(size_t)(r0 + 32) * 2048 + (kt + 1) * 64 + (c0 << 3)];
            }
            __syncthreads();
            const short* Kc = Ks[cur];
            const short* Vc = Vs[cur];
            bf8_t kf0[4], kf1[4];
            #pragma unroll
            for (int sub = 0; sub < 4; ++sub) {
                const int kr = sub * 16 + li;
                kf0[sub] = *(const bf8_t*)&Kc[kr * 64 + ((qd ^ lsw) << 3)];
                kf1[sub] = *(const bf8_t*)&Kc[kr * 64 + (((4 + qd) ^ lsw) << 3)];
            }
            f4_t c[4];
            #pragma unroll
            for (int sub = 0; sub < 4; ++sub) {
                f4_t z; z[0] = z[1] = z[2] = z[3] = 0.f;
                z = MFMA(qf0, kf0[sub], z);
                z = MFMA(qf1, kf1[sub], z);
                c[sub] = z;
            }
            if (kt == qt) {
                #pragma unroll
                for (int sub = 0; sub < 4; ++sub)
                    #pragma unroll
                    for (int r = 0; r < 4; ++r)
                        if (sub * 16 + li > ws * 16 + qd * 4 + r) c[sub][r] = NEG;
            }
            #pragma unroll
            for (int sub = 0; sub < 4; ++sub)
                #pragma unroll
                for (int r = 0; r < 4; ++r) {
                    const float pe = __expf(c[sub][r] - m_[r]) * invl[r];
                    attnp[(size_t)(q0 + qd * 4 + r) * 2048 + kt * 64 + sub * 16 + li] = pe;
                    const int prow = qd * 4 + r;
                    const int pcol = sub * 16 + li;
                    Psw[prow * 64 + (((pcol >> 3) ^ (prow & 7)) << 3) + (pcol & 7)] = (short)f2bf(pe);
                }
            #pragma unroll
            for (int h = 0; h < 2; ++h) {
                bf8_t pa = *(const bf8_t*)&Psw[li * 64 + (((h * 4 + qd) ^ lsw) << 3)];
                #pragma unroll
                for (int d = 0; d < 4; ++d) {
                    bf8_t vf = *(const bf8_t*)&Vc[(d * 16 + li) * 64 + (((h * 4 + qd) ^ lsw) << 3)];
                    o[d] = MFMA(pa, vf, o[d]);
                }
            }
            if (kt < qt) {                      // write-late
                *(float4*)&Ks[cur ^ 1][r0 * 64 + csw] = nka;
                *(float4*)&Ks[cur ^ 1][(r0 + 32) * 64 + csw] = nkb;
                *(float4*)&Vs[cur ^ 1][r0 * 64 + csw] = nva;
                *(float4*)&Vs[cur ^ 1][(r0 + 32) * 64 + csw] = nvb;
                cur ^= 1;
            }
        }
    }

    // zero-fill strictly-above-diagonal region for this wave's 16 rows
    const int w4 = (31 - qt) * 16;   // float4s per row
    const float4 z4 = make_float4(0.f, 0.f, 0.f, 0.f);
    for (int r = 0; r < 16; ++r) {
        float* rp = &attnp[(size_t)(q0 + r) * 2048 + (qt + 1) * 64];
        for (int cc = lane; cc < w4; cc += 64)
            *(float4*)&rp[cc * 4] = z4;
    }

    // O epilogue -> AO bf16 [4096][768]
    const int b = bh / 12, h_ = bh % 12;
    #pragma unroll
    for (int d = 0; d < 4; ++d)
        #pragma unroll
        for (int r = 0; r < 4; ++r)
            AO[(size_t)(b * 2048 + q0 + qd * 4 + r) * 768 + h_ * 64 + d * 16 + li] = f2bf(o[d][r]);
}

// ---------------------------------------------------------------------------
// LayerNorm: out = LN(resid + proj) * gamma + beta, one block per 768-row.
// ---------------------------------------------------------------------------
__global__ __launch_bounds__(256)
void ln_kernel(const float* __restrict__ resid, const float* __restrict__ proj,
               const float* __restrict__ gamma, const float* __restrict__ beta,
               float* __restrict__ out)
{
    __shared__ float red[4];
    const int row = blockIdx.x, t = threadIdx.x;
    const size_t base = (size_t)row * 768;
    float x[3];
    float s = 0.f;
    #pragma unroll
    for (int e = 0; e < 3; ++e) {
        int j = t + e * 256;
        x[e] = resid[base + j] + proj[base + j];
        s += x[e];
    }
    #pragma unroll
    for (int off = 1; off < 64; off <<= 1) s += __shfl_xor(s, off, 64);
    if ((t & 63) == 0) red[t >> 6] = s;
    __syncthreads();
    s = red[0] + red[1] + red[2] + red[3];
    const float mu = s * (1.f / 768.f);
    float vs = 0.f;
    #pragma unroll
    for (int e = 0; e < 3; ++e) { float d = x[e] - mu; vs += d * d; }
    __syncthreads();
    #pragma unroll
    for (int off = 1; off < 64; off <<= 1) vs += __shfl_xor(vs, off, 64);
    if ((t & 63) == 0) red[t >> 6] = vs;
    __syncthreads();
    vs = red[0] + red[1] + red[2] + red[3];
    const float inv = rsqrtf(vs * (1.f / 768.f) + 1e-5f);
    #pragma unroll
    for (int e = 0; e < 3; ++e) {
        int j = t + e * 256;
        out[base + j] = (x[e] - mu) * inv * gamma[j] + beta[j];
    }
}

extern "C" void kernel_launch(void* const* d_in, const int* in_sizes, int n_in,
                              void* d_out, int out_size, void* d_ws, size_t ws_size,
                              hipStream_t stream)
{
    const float* q     = (const float*)d_in[0];
    const float* k     = (const float*)d_in[1];
    const float* v     = (const float*)d_in[2];
    const float* Wq    = (const float*)d_in[4];
    const float* bq    = (const float*)d_in[5];
    const float* Wk    = (const float*)d_in[6];
    const float* bk    = (const float*)d_in[7];
    const float* Wv    = (const float*)d_in[8];
    const float* bv    = (const float*)d_in[9];
    const float* Wo    = (const float*)d_in[10];
    const float* bo    = (const float*)d_in[11];
    const float* gamma = (const float*)d_in[12];
    const float* beta  = (const float*)d_in[13];

    float* out  = (float*)d_out;
    float* attn = out + OUT0_ELEMS;

    short* qc  = (short*)d_ws;
    short* kc  = qc + QKV_ELEMS;
    short* vc  = kc + QKV_ELEMS;
    short* wqc = vc + QKV_ELEMS;
    short* wkc = wqc + W_ELEMS;
    short* wvc = wkc + W_ELEMS;
    short* woc = wvc + W_ELEMS;
    short* Qb  = woc + W_ELEMS;
    short* Kb  = Qb + QKV_ELEMS;
    short* Vt  = Kb + QKV_ELEMS;
    short* AO  = Vt + QKV_ELEMS;
    float* P   = (float*)(AO + QKV_ELEMS);

    CvtP cp;
    cp.s[0] = q;  cp.d[0] = (unsigned short*)qc;  cp.n[0] = (int)QKV_ELEMS;
    cp.s[1] = k;  cp.d[1] = (unsigned short*)kc;  cp.n[1] = (int)QKV_ELEMS;
    cp.s[2] = v;  cp.d[2] = (unsigned short*)vc;  cp.n[2] = (int)QKV_ELEMS;
    cp.s[3] = Wq; cp.d[3] = (unsigned short*)wqc; cp.n[3] = (int)W_ELEMS;
    cp.s[4] = Wk; cp.d[4] = (unsigned short*)wkc; cp.n[4] = (int)W_ELEMS;
    cp.s[5] = Wv; cp.d[5] = (unsigned short*)wvc; cp.n[5] = (int)W_ELEMS;
    cp.s[6] = Wo; cp.d[6] = (unsigned short*)woc; cp.n[6] = (int)W_ELEMS;
    cvt_all<<<dim3(1536, 1, 7), 256, 0, stream>>>(cp);

    GemmP gp;
    gp.A[0] = qc; gp.W[0] = wqc; gp.bias[0] = bq; gp.C[0] = Qb; gp.scale[0] = 0.125f; gp.mode[0] = 0;
    gp.A[1] = kc; gp.W[1] = wkc; gp.bias[1] = bk; gp.C[1] = Kb; gp.scale[1] = 1.f;    gp.mode[1] = 0;
    gp.A[2] = vc; gp.W[2] = wvc; gp.bias[2] = bv; gp.C[2] = Vt; gp.scale[2] = 1.f;    gp.mode[2] = 1;
    gemm_bf16<<<dim3(6, 32, 3), 256, 0, stream>>>(gp);

    attn_fused<<<dim3(768), 256, 0, stream>>>(Qb, Kb, Vt, attn, (unsigned short*)AO);

    GemmP gp2;
    gp2.A[0] = AO; gp2.W[0] = woc; gp2.bias[0] = bo; gp2.C[0] = P; gp2.scale[0] = 1.f; gp2.mode[0] = 2;
    gp2.A[1] = gp2.A[2] = AO; gp2.W[1] = gp2.W[2] = woc; gp2.bias[1] = gp2.bias[2] = bo;
    gp2.C[1] = gp2.C[2] = P; gp2.scale[1] = gp2.scale[2] = 1.f; gp2.mode[1] = gp2.mode[2] = 2;
    gemm_bf16<<<dim3(6, 32, 1), 256, 0, stream>>>(gp2);

    ln_kernel<<<dim3(4096), 256, 0, stream>>>(q, P, gamma, beta, out);
}